// Round 1
// baseline (6403.318 us; speedup 1.0000x reference)
//
#include <hip/hip_runtime.h>
#include <hip/hip_fp16.h>
#include <type_traits>

// LSTM_69879117906487: T=256,B=256,I=1024,H=256,FC=128,C=8
// Round 1: correct fp32 baseline.
//   k_transpose : W_hh [1024,256] -> W_hhT [256,1024] (coalesced per-step reads)
//   k_xg_gemm   : xg = x @ W_ih^T + b_ih + b_hh   [65536,1024], 137 GFLOP
//   k_lstm      : 256-step recurrence, batch-partitioned (no grid sync), fp32
//   k_fc        : relu -> FC1(relu) -> FC2, fused tile kernel

typedef float f4 __attribute__((ext_vector_type(4)));
typedef float f2 __attribute__((ext_vector_type(2)));

__device__ __forceinline__ float ldf(const float* p)  { return *p; }
__device__ __forceinline__ float ldf(const __half* p) { return __half2float(*p); }
__device__ __forceinline__ void  stf(float* p, float v)  { *p = v; }
__device__ __forceinline__ void  stf(__half* p, float v) { *p = __float2half(v); }

__device__ __forceinline__ float fast_sigmoid(float x) {
    return 1.f / (1.f + __expf(-x));
}
__device__ __forceinline__ float fast_tanh(float x) {
    const float e = __expf(-2.f * fabsf(x));
    const float t = (1.f - e) / (1.f + e);
    return copysignf(t, x);
}

// ---------------------------------------------------------------- transpose
__global__ __launch_bounds__(256) void k_transpose(const float* __restrict__ W_hh,
                                                   float* __restrict__ W_hhT) {
    const int idx = blockIdx.x * 256 + threadIdx.x;   // 262144 total
    const int g = idx & 1023;
    const int k = idx >> 10;
    W_hhT[(size_t)k * 1024 + g] = W_hh[(size_t)g * 256 + k];
}

// ---------------------------------------------------------------- xg GEMM
// C[m][n] = sum_k x[m][k] * W_ih[n][k] + (b_ih[n]+b_hh[n]); M=65536,N=1024,K=1024
// 64x64 tile, BK=32, 256 threads, 4x4 per thread.
template <typename XgT>
__global__ __launch_bounds__(256) void k_xg_gemm(
    const float* __restrict__ x, const float* __restrict__ W_ih,
    const float* __restrict__ b_ih, const float* __restrict__ b_hh,
    XgT* __restrict__ xg)
{
    __shared__ __align__(16) float As[32][64];
    __shared__ __align__(16) float Bs[32][64];
    const int tid = threadIdx.x;
    const int n0 = blockIdx.x * 64;
    const int m0 = blockIdx.y * 64;
    const int tx = tid & 15;
    const int ty = tid >> 4;
    const int r  = tid >> 3;   // 0..31
    const int q  = tid & 7;    // float4 column
    float acc[4][4] = {};
    for (int k0 = 0; k0 < 1024; k0 += 32) {
        // issue global loads before the sync (latency hiding)
        const f4 av0 = *(const f4*)&x[(size_t)(m0 + r)      * 1024 + k0 + q * 4];
        const f4 av1 = *(const f4*)&x[(size_t)(m0 + r + 32) * 1024 + k0 + q * 4];
        const f4 bv0 = *(const f4*)&W_ih[(size_t)(n0 + r)      * 1024 + k0 + q * 4];
        const f4 bv1 = *(const f4*)&W_ih[(size_t)(n0 + r + 32) * 1024 + k0 + q * 4];
        __syncthreads();   // previous iteration's LDS reads complete
        #pragma unroll
        for (int c = 0; c < 4; ++c) {
            As[q * 4 + c][r]      = av0[c];
            As[q * 4 + c][r + 32] = av1[c];
            Bs[q * 4 + c][r]      = bv0[c];
            Bs[q * 4 + c][r + 32] = bv1[c];
        }
        __syncthreads();
        #pragma unroll
        for (int kk = 0; kk < 32; ++kk) {
            const f4 a = *(const f4*)&As[kk][ty * 4];
            const f4 b = *(const f4*)&Bs[kk][tx * 4];
            #pragma unroll
            for (int i = 0; i < 4; ++i)
                #pragma unroll
                for (int j = 0; j < 4; ++j)
                    acc[i][j] = fmaf(a[i], b[j], acc[i][j]);
        }
    }
    #pragma unroll
    for (int j = 0; j < 4; ++j) {
        const int n = n0 + tx * 4 + j;
        const float bias = b_ih[n] + b_hh[n];
        #pragma unroll
        for (int i = 0; i < 4; ++i)
            stf(&xg[(size_t)(m0 + ty * 4 + i) * 1024 + n], acc[i][j] + bias);
    }
}

// ---------------------------------------------------------------- recurrence
// 128 blocks x 512 threads; block owns 2 batch rows. Per step:
//   phase1: z[b][g] = xg[t][b][g] + sum_k h[b][k]*W_hhT[k][g]  (thread: 2 cols x 2 b)
//   phase2: gates -> c (reg), h (LDS + global)                 (thread: 1 (b,j))
template <typename XgT, typename HT>
__global__ __launch_bounds__(512) void k_lstm(
    const XgT* __restrict__ xg, const float* __restrict__ W_hhT,
    HT* __restrict__ h_all)
{
    __shared__ __align__(16) float h_lds[2][256];
    __shared__ float z_lds[2][1024];
    const int tid = threadIdx.x;
    const int b0  = blockIdx.x * 2;
    const int g0  = tid * 2;
    const int ub  = tid >> 8;
    const int uj  = tid & 255;
    float c_reg = 0.f;
    if (tid < 256) { h_lds[0][tid] = 0.f; h_lds[1][tid] = 0.f; }
    __syncthreads();
    for (int t = 0; t < 256; ++t) {
        const XgT* xgt = xg + ((size_t)t * 256 + b0) * 1024;
        float a00 = ldf(&xgt[g0]);
        float a01 = ldf(&xgt[g0 + 1]);
        float a10 = ldf(&xgt[1024 + g0]);
        float a11 = ldf(&xgt[1024 + g0 + 1]);
        for (int kc = 0; kc < 64; ++kc) {
            const f4 h0 = *(const f4*)&h_lds[0][kc * 4];   // broadcast b128
            const f4 h1 = *(const f4*)&h_lds[1][kc * 4];
            #pragma unroll
            for (int kk = 0; kk < 4; ++kk) {
                const f2 w = *(const f2*)&W_hhT[(size_t)(kc * 4 + kk) * 1024 + g0];
                a00 = fmaf(h0[kk], w[0], a00);
                a01 = fmaf(h0[kk], w[1], a01);
                a10 = fmaf(h1[kk], w[0], a10);
                a11 = fmaf(h1[kk], w[1], a11);
            }
        }
        z_lds[0][g0] = a00; z_lds[0][g0 + 1] = a01;
        z_lds[1][g0] = a10; z_lds[1][g0 + 1] = a11;
        __syncthreads();   // z complete; h_lds reads complete
        const float zi = z_lds[ub][uj];
        const float zf = z_lds[ub][256 + uj];
        const float zg = z_lds[ub][512 + uj];
        const float zo = z_lds[ub][768 + uj];
        const float ig = fast_sigmoid(zi);
        const float fg = fast_sigmoid(zf);
        const float gg = fast_tanh(zg);
        const float og = fast_sigmoid(zo);
        c_reg = fg * c_reg + ig * gg;
        const float hv = og * fast_tanh(c_reg);
        h_lds[ub][uj] = hv;
        stf(&h_all[((size_t)t * 256 + b0 + ub) * 256 + uj], hv);
        __syncthreads();   // h ready for next step; z_lds safe to overwrite
    }
}

// ---------------------------------------------------------------- FC1+FC2
// per block: 64 rows. fc1 = relu(relu(h) @ W1^T + b1) in regs, FC2 via LDS.
template <typename HT>
__global__ __launch_bounds__(256) void k_fc(
    const HT* __restrict__ h_all, const float* __restrict__ W1,
    const float* __restrict__ b1, const float* __restrict__ W2,
    const float* __restrict__ b2, float* __restrict__ out)
{
    __shared__ __align__(16) float smem[12288];   // 48 KB, re-used
    float* hsT = smem;          // [64 k][64 r]
    float* w1T = smem + 4096;   // [64 k][128 f]
    const int tid = threadIdx.x;
    const int m0 = blockIdx.x * 64;
    const int tx = tid & 15;
    const int ty = tid >> 4;
    const int r0 = ty * 4;
    const int fA = tx * 4;        // f columns 0..63
    const int fB = 64 + tx * 4;   // f columns 64..127
    float acc[4][8] = {};
    for (int kc = 0; kc < 4; ++kc) {
        const int k0 = kc * 64;
        __syncthreads();
        #pragma unroll
        for (int i = 0; i < 4; ++i) {
            const int fid = tid + i * 256;   // 1024 float4s of h chunk
            const int rr = fid >> 4;
            const int qq = fid & 15;
            const HT* p = &h_all[(size_t)(m0 + rr) * 256 + k0 + qq * 4];
            f4 v;
            if constexpr (std::is_same<HT, float>::value) {
                v = *(const f4*)p;
            } else {
                v[0] = ldf(p); v[1] = ldf(p + 1); v[2] = ldf(p + 2); v[3] = ldf(p + 3);
            }
            #pragma unroll
            for (int c = 0; c < 4; ++c)
                hsT[(qq * 4 + c) * 64 + rr] = fmaxf(v[c], 0.f);   // relu(h)
        }
        #pragma unroll
        for (int i = 0; i < 8; ++i) {
            const int fid = tid + i * 256;   // 2048 float4s of W1 chunk
            const int ff = fid >> 4;
            const int qq = fid & 15;
            const f4 v = *(const f4*)&W1[(size_t)ff * 256 + k0 + qq * 4];
            #pragma unroll
            for (int c = 0; c < 4; ++c)
                w1T[(qq * 4 + c) * 128 + ff] = v[c];
        }
        __syncthreads();
        #pragma unroll 4
        for (int kk = 0; kk < 64; ++kk) {
            const f4 a  = *(const f4*)&hsT[kk * 64 + r0];
            const f4 ba = *(const f4*)&w1T[kk * 128 + fA];
            const f4 bb = *(const f4*)&w1T[kk * 128 + fB];
            #pragma unroll
            for (int i = 0; i < 4; ++i) {
                #pragma unroll
                for (int j = 0; j < 4; ++j) {
                    acc[i][j]     = fmaf(a[i], ba[j], acc[i][j]);
                    acc[i][j + 4] = fmaf(a[i], bb[j], acc[i][j + 4]);
                }
            }
        }
    }
    __syncthreads();
    float* fc1s = smem;   // [64][132] padded
    #pragma unroll
    for (int j = 0; j < 4; ++j) {
        const float bbA = b1[fA + j];
        const float bbB = b1[fB + j];
        #pragma unroll
        for (int i = 0; i < 4; ++i) {
            fc1s[(r0 + i) * 132 + fA + j] = fmaxf(acc[i][j] + bbA, 0.f);
            fc1s[(r0 + i) * 132 + fB + j] = fmaxf(acc[i][j + 4] + bbB, 0.f);
        }
    }
    __syncthreads();
    const int r  = tid >> 2;          // 0..63
    const int c0 = (tid & 3) * 2;     // 0,2,4,6
    float o0 = b2[c0], o1 = b2[c0 + 1];
    #pragma unroll
    for (int fq = 0; fq < 32; ++fq) {
        const f4 p  = *(const f4*)&fc1s[r * 132 + fq * 4];
        const f4 wa = *(const f4*)&W2[(size_t)c0 * 128 + fq * 4];
        const f4 wb = *(const f4*)&W2[(size_t)(c0 + 1) * 128 + fq * 4];
        o0 += p[0] * wa[0] + p[1] * wa[1] + p[2] * wa[2] + p[3] * wa[3];
        o1 += p[0] * wb[0] + p[1] * wb[1] + p[2] * wb[2] + p[3] * wb[3];
    }
    out[(size_t)(m0 + r) * 8 + c0]     = o0;
    out[(size_t)(m0 + r) * 8 + c0 + 1] = o1;
}

// ---------------------------------------------------------------- launch
extern "C" void kernel_launch(void* const* d_in, const int* in_sizes, int n_in,
                              void* d_out, int out_size, void* d_ws, size_t ws_size,
                              hipStream_t stream)
{
    const float* x    = (const float*)d_in[0];
    const float* W_ih = (const float*)d_in[1];
    const float* W_hh = (const float*)d_in[2];
    const float* b_ih = (const float*)d_in[3];
    const float* b_hh = (const float*)d_in[4];
    const float* W1   = (const float*)d_in[5];
    const float* b1   = (const float*)d_in[6];
    const float* W2   = (const float*)d_in[7];
    const float* b2   = (const float*)d_in[8];
    float* out = (float*)d_out;
    char* ws = (char*)d_ws;

    const size_t XG_F32 = (size_t)65536 * 1024 * 4;   // 268 MB
    const size_t XG_F16 = XG_F32 / 2;
    const size_t WT     = (size_t)256 * 1024 * 4;     // 1 MB
    const size_t H_F32  = (size_t)65536 * 256 * 4;    // 67 MB
    const size_t H_F16  = H_F32 / 2;

    const dim3 gA(16, 1024), bA(256);

    if (ws_size >= XG_F32 + WT + H_F32) {
        // full fp32 scratch (preferred)
        float* xg    = (float*)ws;
        float* W_hhT = (float*)(ws + XG_F32);
        float* h_all = (float*)(ws + XG_F32 + WT);
        k_transpose<<<1024, 256, 0, stream>>>(W_hh, W_hhT);
        k_xg_gemm<float><<<gA, bA, 0, stream>>>(x, W_ih, b_ih, b_hh, xg);
        k_lstm<float, float><<<128, 512, 0, stream>>>(xg, W_hhT, h_all);
        k_fc<float><<<1024, 256, 0, stream>>>(h_all, W1, b1, W2, b2, out);
    } else if (ws_size >= XG_F16 + WT + H_F32) {
        // fp16 xg storage, fp32 h
        __half* xg   = (__half*)ws;
        float* W_hhT = (float*)(ws + XG_F16);
        float* h_all = (float*)(ws + XG_F16 + WT);
        k_transpose<<<1024, 256, 0, stream>>>(W_hh, W_hhT);
        k_xg_gemm<__half><<<gA, bA, 0, stream>>>(x, W_ih, b_ih, b_hh, xg);
        k_lstm<__half, float><<<128, 512, 0, stream>>>(xg, W_hhT, h_all);
        k_fc<float><<<1024, 256, 0, stream>>>(h_all, W1, b1, W2, b2, out);
    } else {
        // fp16 xg + fp16 h (minimum footprint: ~169 MB)
        __half* xg    = (__half*)ws;
        float*  W_hhT = (float*)(ws + XG_F16);
        __half* h_all = (__half*)(ws + XG_F16 + WT);
        k_transpose<<<1024, 256, 0, stream>>>(W_hh, W_hhT);
        k_xg_gemm<__half><<<gA, bA, 0, stream>>>(x, W_ih, b_ih, b_hh, xg);
        k_lstm<__half, __half><<<128, 512, 0, stream>>>(xg, W_hhT, h_all);
        k_fc<__half><<<1024, 256, 0, stream>>>(h_all, W1, b1, W2, b2, out);
    }
}

// Round 2
// 2323.430 us; speedup vs baseline: 2.7560x; 2.7560x over previous
//
#include <hip/hip_runtime.h>
#include <type_traits>

// LSTM_69879117906487: T=256,B=256,I=1024,H=256,FC=128,C=8
// Round 2: MFMA fp16 everywhere on the matmul paths.
//   k_bias      : bias = b_ih + b_hh
//   k_pack      : W_hh -> MFMA B-fragment-packed fp16 (512 KB)
//   k_xg_mfma   : xg = x @ W_ih^T + bias, fp16 MFMA, 128x128 tile
//   k_lstm_mfma : 16 blocks x 8 waves, h in LDS fp16, gates in-register
//   k_fc        : relu -> FC1(relu) -> FC2 (fp32 VALU, reads fp16 h_all)

typedef float  f4    __attribute__((ext_vector_type(4)));
typedef float  f32x4 __attribute__((ext_vector_type(4)));
typedef _Float16 h8  __attribute__((ext_vector_type(8)));

__device__ __forceinline__ float ldf(const float* p)    { return *p; }
__device__ __forceinline__ float ldf(const _Float16* p) { return (float)*p; }

__device__ __forceinline__ float fast_sigmoid(float x) {
    return 1.f / (1.f + __expf(-x));
}
__device__ __forceinline__ float fast_tanh(float x) {
    const float e = __expf(-2.f * fabsf(x));
    const float t = (1.f - e) / (1.f + e);
    return copysignf(t, x);
}

// ---------------------------------------------------------------- bias
__global__ __launch_bounds__(256) void k_bias(const float* __restrict__ b_ih,
                                              const float* __restrict__ b_hh,
                                              float* __restrict__ bias) {
    const int i = blockIdx.x * 256 + threadIdx.x;
    if (i < 1024) bias[i] = b_ih[i] + b_hh[i];
}

// ---------------------------------------------------------------- W_hh pack
// W_pack fragment fi = gt*8 + kb (gt: 16-gate tile, kb: 32-k block).
// Lane l, elem j holds W_hh[g][k], g = gt*16 + (l&15), k = kb*32 + (l>>4)*8 + j.
// Each lane's 8 elements are contiguous 16B -> global b128 loads in k_lstm.
__global__ __launch_bounds__(256) void k_pack(const float* __restrict__ W_hh,
                                              _Float16* __restrict__ Wp) {
    const int idx = blockIdx.x * 256 + threadIdx.x;   // fi*64 + l, 32768 total
    const int fi = idx >> 6;
    const int l  = idx & 63;
    const int g  = (fi >> 3) * 16 + (l & 15);
    const int k  = (fi & 7) * 32 + ((l >> 4) << 3);
    const float* src = &W_hh[(size_t)g * 256 + k];
    h8 v;
    #pragma unroll
    for (int c = 0; c < 8; ++c) v[c] = (_Float16)src[c];
    *(h8*)&Wp[(size_t)idx * 8] = v;
}

// ---------------------------------------------------------------- xg GEMM (MFMA)
// z[m][n] = sum_k x[m][k]*W_ih[n][k] + bias[n]; M=65536,N=1024,K=1024.
// 128x128 tile, BK=32, 256 thr (4 waves, each 64x64). Reg-staged fp32->fp16.
__global__ __launch_bounds__(256) void k_xg_mfma(
    const float* __restrict__ x, const float* __restrict__ W_ih,
    const float* __restrict__ bias, _Float16* __restrict__ xg)
{
    __shared__ _Float16 As[2][128][40];   // pad 40: 80B row stride, 16B-aligned
    __shared__ _Float16 Bs[2][128][40];
    const int tid = threadIdx.x;
    const int l   = tid & 63;
    const int w   = tid >> 6;
    const int m0  = blockIdx.y * 128;
    const int n0  = blockIdx.x * 128;
    const int wr  = (w >> 1) * 64;
    const int wc  = (w & 1) * 64;
    const int srow = tid >> 2;          // staging row 0..63 (+64 for seg 1)
    const int skof = (tid & 3) * 8;     // staging k offset
    const int lr = l & 15;
    const int lk = (l >> 4) * 8;

    f32x4 acc[4][4] = {};
    f4 ldA[2][2], ldB[2][2];

    auto XG_LOAD = [&](int kt) {
        const int k0 = kt * 32;
        #pragma unroll
        for (int s = 0; s < 2; ++s) {
            const float* xa = &x[(size_t)(m0 + srow + s * 64) * 1024 + k0 + skof];
            const float* wb = &W_ih[(size_t)(n0 + srow + s * 64) * 1024 + k0 + skof];
            ldA[s][0] = *(const f4*)xa; ldA[s][1] = *(const f4*)(xa + 4);
            ldB[s][0] = *(const f4*)wb; ldB[s][1] = *(const f4*)(wb + 4);
        }
    };
    auto XG_WRITE = [&](int buf) {
        #pragma unroll
        for (int s = 0; s < 2; ++s) {
            h8 va, vb;
            #pragma unroll
            for (int c = 0; c < 8; ++c) {
                va[c] = (_Float16)ldA[s][c >> 2][c & 3];
                vb[c] = (_Float16)ldB[s][c >> 2][c & 3];
            }
            *(h8*)&As[buf][srow + s * 64][skof] = va;
            *(h8*)&Bs[buf][srow + s * 64][skof] = vb;
        }
    };

    XG_LOAD(0);
    XG_WRITE(0);
    __syncthreads();
    for (int kt = 0; kt < 32; ++kt) {
        const int cur = kt & 1;
        if (kt + 1 < 32) XG_LOAD(kt + 1);
        h8 af[4], bf[4];
        #pragma unroll
        for (int mf = 0; mf < 4; ++mf) af[mf] = *(const h8*)&As[cur][wr + mf * 16 + lr][lk];
        #pragma unroll
        for (int nf = 0; nf < 4; ++nf) bf[nf] = *(const h8*)&Bs[cur][wc + nf * 16 + lr][lk];
        #pragma unroll
        for (int mf = 0; mf < 4; ++mf)
            #pragma unroll
            for (int nf = 0; nf < 4; ++nf)
                acc[mf][nf] = __builtin_amdgcn_mfma_f32_16x16x32_f16(af[mf], bf[nf], acc[mf][nf], 0, 0, 0);
        if (kt + 1 < 32) XG_WRITE((kt + 1) & 1);
        __syncthreads();
    }
    // epilogue: C layout col=l&15, row=(l>>4)*4+reg
    #pragma unroll
    for (int nf = 0; nf < 4; ++nf) {
        const int col = n0 + wc + nf * 16 + lr;
        const float bv = bias[col];
        #pragma unroll
        for (int mf = 0; mf < 4; ++mf) {
            #pragma unroll
            for (int r = 0; r < 4; ++r) {
                const int row = m0 + wr + mf * 16 + (l >> 4) * 4 + r;
                xg[(size_t)row * 1024 + col] = (_Float16)(acc[mf][nf][r] + bv);
            }
        }
    }
}

// ---------------------------------------------------------------- recurrence (MFMA)
// 16 blocks x 512 thr (8 waves). Block owns 16 batch rows, all 1024 gates.
// Wave w owns gate tiles gt = w + 16c + 8d (c=chunk i/f/g/o, d=half) so each
// lane ends up with i,f,g,o for the same (batch,j) -> gates fully in-register.
__global__ __launch_bounds__(512) void k_lstm_mfma(
    const _Float16* __restrict__ xg, const _Float16* __restrict__ Wp,
    _Float16* __restrict__ h_all)
{
    __shared__ _Float16 h_sh[2][16][264];   // 528B row stride (16B-aligned)
    const int tid = threadIdx.x;
    const int w  = tid >> 6;
    const int l  = tid & 63;
    const int lr = l & 15;
    const int lg = l >> 4;
    const int b0 = blockIdx.x * 16;

    {   // zero both h buffers
        _Float16* p = &h_sh[0][0][0];
        for (int i = tid; i < 2 * 16 * 264; i += 512) p[i] = (_Float16)0.f;
    }
    __syncthreads();

    float cst[2][4] = {};
    const int crow = tid >> 5;          // h_all copy: row 0..15
    const int ccol = (tid & 31) * 8;    // col 0..248

    for (int t = 0; t < 256; ++t) {
        const int cur = t & 1;
        const int nxt = cur ^ 1;
        const _Float16* xgt = xg + ((size_t)t * 256 + b0) * 1024;

        // 1) prefetch this step's xg values (acc init), issued early
        float xv[8][4];
        #pragma unroll
        for (int m = 0; m < 8; ++m) {
            const int c = m >> 1, d = m & 1;
            const int gate = c * 256 + d * 128 + w * 16 + lr;
            #pragma unroll
            for (int r = 0; r < 4; ++r)
                xv[m][r] = (float)xgt[(size_t)(lg * 4 + r) * 1024 + gate];
        }
        // 2) A fragments (h) from LDS
        h8 a[8];
        #pragma unroll
        for (int kb = 0; kb < 8; ++kb)
            a[kb] = *(const h8*)&h_sh[cur][lr][kb * 32 + lg * 8];
        // 3) z = xg + h @ W_hh^T via MFMA (B frags streamed from L2)
        f32x4 accs[8];
        #pragma unroll
        for (int m = 0; m < 8; ++m) {
            const int c = m >> 1, d = m & 1;
            const int gt = w + 16 * c + 8 * d;
            f32x4 acc;
            acc[0] = xv[m][0]; acc[1] = xv[m][1]; acc[2] = xv[m][2]; acc[3] = xv[m][3];
            #pragma unroll
            for (int kb = 0; kb < 8; ++kb) {
                const h8 bfrag = *(const h8*)&Wp[((size_t)(gt * 8 + kb) * 64 + l) * 8];
                acc = __builtin_amdgcn_mfma_f32_16x16x32_f16(a[kb], bfrag, acc, 0, 0, 0);
            }
            accs[m] = acc;
        }
        // 4) gates -> c, h (all in-register; write h to LDS for next step)
        #pragma unroll
        for (int d = 0; d < 2; ++d) {
            #pragma unroll
            for (int r = 0; r < 4; ++r) {
                const float ig = fast_sigmoid(accs[0 * 2 + d][r]);
                const float fg = fast_sigmoid(accs[1 * 2 + d][r]);
                const float gg = fast_tanh(accs[2 * 2 + d][r]);
                const float og = fast_sigmoid(accs[3 * 2 + d][r]);
                cst[d][r] = fg * cst[d][r] + ig * gg;
                const float hv = og * fast_tanh(cst[d][r]);
                h_sh[nxt][lg * 4 + r][d * 128 + w * 16 + lr] = (_Float16)hv;
            }
        }
        __syncthreads();   // the ONLY barrier per step
        // 5) coalesced h_sh[nxt] -> h_all[t] (b128 per thread)
        *(h8*)&h_all[((size_t)t * 256 + b0 + crow) * 256 + ccol] =
            *(const h8*)&h_sh[nxt][crow][ccol];
    }
}

// ---------------------------------------------------------------- FC1+FC2
template <typename HT>
__global__ __launch_bounds__(256) void k_fc(
    const HT* __restrict__ h_all, const float* __restrict__ W1,
    const float* __restrict__ b1, const float* __restrict__ W2,
    const float* __restrict__ b2, float* __restrict__ out)
{
    __shared__ __align__(16) float smem[12288];   // 48 KB, re-used
    float* hsT = smem;          // [64 k][64 r]
    float* w1T = smem + 4096;   // [64 k][128 f]
    const int tid = threadIdx.x;
    const int m0 = blockIdx.x * 64;
    const int tx = tid & 15;
    const int ty = tid >> 4;
    const int r0 = ty * 4;
    const int fA = tx * 4;
    const int fB = 64 + tx * 4;
    float acc[4][8] = {};
    for (int kc = 0; kc < 4; ++kc) {
        const int k0 = kc * 64;
        __syncthreads();
        #pragma unroll
        for (int i = 0; i < 4; ++i) {
            const int fid = tid + i * 256;
            const int rr = fid >> 4;
            const int qq = fid & 15;
            const HT* p = &h_all[(size_t)(m0 + rr) * 256 + k0 + qq * 4];
            f4 v;
            if constexpr (std::is_same<HT, float>::value) {
                v = *(const f4*)p;
            } else {
                v[0] = ldf(p); v[1] = ldf(p + 1); v[2] = ldf(p + 2); v[3] = ldf(p + 3);
            }
            #pragma unroll
            for (int c = 0; c < 4; ++c)
                hsT[(qq * 4 + c) * 64 + rr] = fmaxf(v[c], 0.f);
        }
        #pragma unroll
        for (int i = 0; i < 8; ++i) {
            const int fid = tid + i * 256;
            const int ff = fid >> 4;
            const int qq = fid & 15;
            const f4 v = *(const f4*)&W1[(size_t)ff * 256 + k0 + qq * 4];
            #pragma unroll
            for (int c = 0; c < 4; ++c)
                w1T[(qq * 4 + c) * 128 + ff] = v[c];
        }
        __syncthreads();
        #pragma unroll 4
        for (int kk = 0; kk < 64; ++kk) {
            const f4 aa = *(const f4*)&hsT[kk * 64 + r0];
            const f4 ba = *(const f4*)&w1T[kk * 128 + fA];
            const f4 bb = *(const f4*)&w1T[kk * 128 + fB];
            #pragma unroll
            for (int i = 0; i < 4; ++i) {
                #pragma unroll
                for (int j = 0; j < 4; ++j) {
                    acc[i][j]     = fmaf(aa[i], ba[j], acc[i][j]);
                    acc[i][j + 4] = fmaf(aa[i], bb[j], acc[i][j + 4]);
                }
            }
        }
    }
    __syncthreads();
    float* fc1s = smem;   // [64][132]
    #pragma unroll
    for (int j = 0; j < 4; ++j) {
        const float bbA = b1[fA + j];
        const float bbB = b1[fB + j];
        #pragma unroll
        for (int i = 0; i < 4; ++i) {
            fc1s[(r0 + i) * 132 + fA + j] = fmaxf(acc[i][j] + bbA, 0.f);
            fc1s[(r0 + i) * 132 + fB + j] = fmaxf(acc[i][j + 4] + bbB, 0.f);
        }
    }
    __syncthreads();
    const int r  = tid >> 2;
    const int c0 = (tid & 3) * 2;
    float o0 = b2[c0], o1 = b2[c0 + 1];
    #pragma unroll
    for (int fq = 0; fq < 32; ++fq) {
        const f4 p  = *(const f4*)&fc1s[r * 132 + fq * 4];
        const f4 wa = *(const f4*)&W2[(size_t)c0 * 128 + fq * 4];
        const f4 wb = *(const f4*)&W2[(size_t)(c0 + 1) * 128 + fq * 4];
        o0 += p[0] * wa[0] + p[1] * wa[1] + p[2] * wa[2] + p[3] * wa[3];
        o1 += p[0] * wb[0] + p[1] * wb[1] + p[2] * wb[2] + p[3] * wb[3];
    }
    out[(size_t)(m0 + r) * 8 + c0]     = o0;
    out[(size_t)(m0 + r) * 8 + c0 + 1] = o1;
}

// ---------------------------------------------------------------- launch
extern "C" void kernel_launch(void* const* d_in, const int* in_sizes, int n_in,
                              void* d_out, int out_size, void* d_ws, size_t ws_size,
                              hipStream_t stream)
{
    const float* x    = (const float*)d_in[0];
    const float* W_ih = (const float*)d_in[1];
    const float* W_hh = (const float*)d_in[2];
    const float* b_ih = (const float*)d_in[3];
    const float* b_hh = (const float*)d_in[4];
    const float* W1   = (const float*)d_in[5];
    const float* b1   = (const float*)d_in[6];
    const float* W2   = (const float*)d_in[7];
    const float* b2   = (const float*)d_in[8];
    float* out = (float*)d_out;
    char* ws = (char*)d_ws;

    // workspace layout (168.3 MB total)
    _Float16* xg    = (_Float16*)ws;                          // 134,217,728 B
    _Float16* h_all = (_Float16*)(ws + 134217728);            //  33,554,432 B
    _Float16* Wp    = (_Float16*)(ws + 167772160);            //     524,288 B
    float*    bias  = (float*)   (ws + 168296448);            //       4,096 B

    k_bias<<<4, 256, 0, stream>>>(b_ih, b_hh, bias);
    k_pack<<<128, 256, 0, stream>>>(W_hh, Wp);
    k_xg_mfma<<<dim3(8, 512), 256, 0, stream>>>(x, W_ih, bias, xg);
    k_lstm_mfma<<<16, 512, 0, stream>>>(xg, Wp, h_all);
    k_fc<_Float16><<<1024, 256, 0, stream>>>(h_all, W1, b1, W2, b2, out);
}